// Round 23
// baseline (173.446 us; speedup 1.0000x reference)
//
#include <hip/hip_runtime.h>

#define CIN 8
#define COUT 32
#define NR 2
#define EPSF 1e-6f

#define BSH 5                   // log2 nodes per bucket
#define BNODES 32               // nodes per bucket
#define NBMAX 2048              // supports N <= 65536
#define CHUNK 4096              // edges per binify block
#define BINT 512                // binify threads
#define BREG (CHUNK / BINT)     // staged edges per binify thread
#define IDBITS 21               // supports E < 2^21
#define IDMASK ((1u << IDBITS) - 1u)
#define SRCMASK 0x03FFFFFFu     // low 26 bits of meta = src node
#define PSTAGE 1792             // per-bucket staging capacity (avg 1024)
#define FTH 512                 // fused kernel threads (64 teams, 2 per node)
#define AR2 ((PSTAGE + FTH - 1) / FTH)   // phase-A records per thread

// ---------------- pass 1: coarse bucket histogram ----------------
__global__ __launch_bounds__(256) void bucket_hist(
    const int* __restrict__ eidx, int* __restrict__ bucketCnt, int E, int nb)
{
    __shared__ int cnt[NBMAX];
    for (int i = threadIdx.x; i < nb; i += 256) cnt[i] = 0;
    __syncthreads();
    for (int e = blockIdx.x * 256 + threadIdx.x; e < E; e += gridDim.x * 256)
        atomicAdd(&cnt[eidx[E + e] >> BSH], 1);
    __syncthreads();
    for (int i = threadIdx.x; i < nb; i += 256)
        if (cnt[i]) atomicAdd(&bucketCnt[i], cnt[i]);
}

// ---------------- pass 2: single-block scan -> bucket bases ----------------
__global__ __launch_bounds__(1024) void scan_init(
    const int* __restrict__ bucketCnt, int* __restrict__ bucketBase,
    int* __restrict__ gCursor, int nb)
{
    __shared__ int sA[NBMAX], sB[NBMAX];
    for (int i = threadIdx.x; i < NBMAX; i += 1024)
        sA[i] = (i < nb) ? bucketCnt[i] : 0;
    __syncthreads();
    int* src = sA; int* dst = sB;
    for (int off = 1; off < NBMAX; off <<= 1) {
        for (int i = threadIdx.x; i < NBMAX; i += 1024)
            dst[i] = src[i] + (i >= off ? src[i - off] : 0);
        __syncthreads();
        int* tmp = src; src = dst; dst = tmp;
    }
    for (int i = threadIdx.x; i < nb; i += 1024) {
        int incl = src[i];
        int base = incl - bucketCnt[i];
        bucketBase[i] = base;
        gCursor[i] = base;
        if (i == nb - 1) bucketBase[nb] = incl;
    }
}

// ------- pass 3: bin edges by bucket; fast hierarchical scan --------
template<bool PACKED>
__global__ __launch_bounds__(BINT) void binify(
    const int* __restrict__ eidx, int* __restrict__ gCursor,
    unsigned* __restrict__ outMeta,     // PACKED: (dl<<26)|src ; else (dl<<21)|e
    float4*   __restrict__ pcmpS,       // PACKED only: reordered pcmp
    const float* __restrict__ pcmp, int E, int nb)
{
    __shared__ int cnt[NBMAX];
    __shared__ int sIncl[NBMAX];
    __shared__ int gbase[NBMAX];
    __shared__ int wsum[8];
    __shared__ unsigned sid[CHUNK];
    __shared__ unsigned short bucketOf[CHUNK];

    const int e0 = blockIdx.x * CHUNK;
    const int num = min(CHUNK, E - e0);
    const int t = threadIdx.x;
    const int lane = t & 63, wid = t >> 6;

    for (int i = t; i < nb; i += BINT) cnt[i] = 0;
    __syncthreads();

    int dreg[BREG];
#pragma unroll
    for (int kk = 0; kk < BREG; ++kk) {
        int k = t + kk * BINT;
        if (k < num) {
            dreg[kk] = eidx[E + e0 + k];
            atomicAdd(&cnt[dreg[kk] >> BSH], 1);
        }
    }
    __syncthreads();

    {
        int j0 = t * 4;
        int v0 = (j0 + 0 < nb) ? cnt[j0 + 0] : 0;
        int v1 = (j0 + 1 < nb) ? cnt[j0 + 1] : 0;
        int v2 = (j0 + 2 < nb) ? cnt[j0 + 2] : 0;
        int v3 = (j0 + 3 < nb) ? cnt[j0 + 3] : 0;
        int p0 = v0, p1 = p0 + v1, p2 = p1 + v2, p3 = p2 + v3;
        int incl = p3;
#pragma unroll
        for (int off = 1; off < 64; off <<= 1) {
            int u = __shfl_up(incl, off, 64);
            if (lane >= off) incl += u;
        }
        int laneEx = incl - p3;
        if (lane == 63) wsum[wid] = incl;
        __syncthreads();
        if (t == 0) {
            int acc = 0;
#pragma unroll
            for (int i = 0; i < 8; ++i) { int w = wsum[i]; wsum[i] = acc; acc += w; }
        }
        __syncthreads();
        int off0 = wsum[wid] + laneEx;
        sIncl[j0 + 0] = off0 + p0;
        sIncl[j0 + 1] = off0 + p1;
        sIncl[j0 + 2] = off0 + p2;
        sIncl[j0 + 3] = off0 + p3;
    }
    __syncthreads();

    for (int b = t; b < nb; b += BINT) {
        int c = sIncl[b] - (b ? sIncl[b - 1] : 0);
        gbase[b] = c ? atomicAdd(&gCursor[b], c) : 0;
    }
    __syncthreads();
    for (int i = t; i < nb; i += BINT) cnt[i] = 0;   // reuse as cursor
    __syncthreads();

#pragma unroll
    for (int kk = 0; kk < BREG; ++kk) {
        int k = t + kk * BINT;
        if (k < num) {
            int e = e0 + k;
            int d = dreg[kk];
            int b = d >> BSH;
            int slot = (b ? sIncl[b - 1] : 0) + atomicAdd(&cnt[b], 1);
            sid[slot] = ((unsigned)(d & (BNODES - 1)) << IDBITS) | (unsigned)e;
            bucketOf[slot] = (unsigned short)b;
        }
    }
    __syncthreads();

    for (int s = t; s < num; s += BINT) {
        int b = bucketOf[s];
        int intra = s - (b ? sIncl[b - 1] : 0);
        unsigned v = sid[s];
        int pos = gbase[b] + intra;
        if (PACKED) {
            int id = v & IDMASK;
            unsigned dl = v >> IDBITS;
            unsigned sv = (unsigned)eidx[id];
            outMeta[pos] = (dl << 26) | sv;
            pcmpS[pos] = *reinterpret_cast<const float4*>(pcmp + (size_t)id * 4);
        } else {
            outMeta[pos] = v;
        }
    }
}

// ---- pass 4: 512-thread light-LDS kernel. 64 teams x 8 lanes; 2 teams/node.
template<bool SRC16>
__global__ __launch_bounds__(FTH, 8) void fused_team_kernel(
    const float* __restrict__ x,          // [N, CIN]
    const float4* __restrict__ pcmpS,     // reordered pcmp, bucket-segmented
    const unsigned* __restrict__ meta,    // (dl<<26)|src per slot
    const int* __restrict__ bucketBase,   // [nb+1]
    const float* __restrict__ W_rad, const float* __restrict__ phase,
    const float* __restrict__ b_nl,
    const float* __restrict__ W1, const float* __restrict__ b1,
    const float* __restrict__ W2, const float* __restrict__ b2,
    const float* __restrict__ W3, const float* __restrict__ b3,
    float* __restrict__ out, int N)
{
    __shared__ float sWrad[NR * CIN][COUT];          // 2 KB
    __shared__ float sPh[COUT][2];
    __shared__ float sBias[4][COUT];
    __shared__ unsigned srtPk[PSTAGE];               // 7 KB
    __shared__ unsigned short srtK[SRC16 ? 2 : PSTAGE];
    __shared__ float Qbuf[2][BNODES][33];            // 8.4 KB (two halves)
    __shared__ int cnt[BNODES], segS[BNODES], padL[BNODES], cur[BNODES];

    for (int i = threadIdx.x; i < NR * CIN * COUT; i += FTH) ((float*)sWrad)[i] = W_rad[i];
    if (threadIdx.x < COUT) {
        float sn, cs; __sincosf(phase[threadIdx.x], &sn, &cs);
        sPh[threadIdx.x][0] = cs; sPh[threadIdx.x][1] = sn;
        sBias[0][threadIdx.x] = b_nl[threadIdx.x];
        sBias[1][threadIdx.x] = b1[threadIdx.x];
        sBias[2][threadIdx.x] = b2[threadIdx.x];
        sBias[3][threadIdx.x] = b3[threadIdx.x];
    }
    if (threadIdx.x < BNODES) cnt[threadIdx.x] = 0;

    const int start = bucketBase[blockIdx.x];
    const int total = bucketBase[blockIdx.x + 1] - start;
    const bool fb = (total > PSTAGE);    // block-uniform fallback flag
    __syncthreads();

    // ---- phase A: coalesced meta load into registers, LDS histogram ----
    unsigned mreg[AR2];
    const int staged = fb ? 0 : total;
#pragma unroll
    for (int kk = 0; kk < AR2; ++kk) {
        int k = threadIdx.x + kk * FTH;
        if (k < staged) {
            mreg[kk] = meta[start + k];
            atomicAdd(&cnt[mreg[kk] >> 26], 1);
        }
    }
    __syncthreads();

    // ---- phase B: exclusive scan (raw counts) + 8-node group max ----
    if (threadIdx.x < BNODES) {
        int v = cnt[threadIdx.x];
        int m = v;
        m = max(m, __shfl_xor(m, 1, 32));
        m = max(m, __shfl_xor(m, 2, 32));
        m = max(m, __shfl_xor(m, 4, 32));   // max over aligned 8-node group
        int incl = v;
#pragma unroll
        for (int off = 1; off < BNODES; off <<= 1) {
            int u = __shfl_up(incl, off, 32);
            if ((int)threadIdx.x >= off) incl += u;
        }
        segS[threadIdx.x] = incl - v;
        cur[threadIdx.x]  = incl - v;
        padL[threadIdx.x] = m;
    }
    __syncthreads();

    // ---- phase C: scatter sort tokens into node-sorted LDS ----
    if (!fb) {
#pragma unroll
        for (int kk = 0; kk < AR2; ++kk) {
            int k = threadIdx.x + kk * FTH;
            if (k < staged) {
                unsigned m = mreg[kk];
                int pos = atomicAdd(&cur[m >> 26], 1);
                if (SRC16) {
                    srtPk[pos] = ((unsigned)k << 16) | (m & 0xFFFFu);
                } else {
                    srtPk[pos] = m & SRCMASK;
                    srtK[pos] = (unsigned short)k;
                }
            }
        }
    }
    __syncthreads();

    const int c    = threadIdx.x & 31;    // half-wave lane
    const int sub  = threadIdx.x >> 5;    // half-wave 0..15
    const int team4 = c >> 3;             // 0..3
    const int il   = c & 7;               // input channel i
    const int gl   = (sub & 7) * 4 + team4;  // node slot 0..31
    const int half = sub >> 3;            // 0 or 1 (wave-uniform)
    const int node0 = blockIdx.x << BSH;

    // ---- team accumulation: stride-2 edge split between the two halves ----
    float4 qa = {0.f, 0.f, 0.f, 0.f};
    if (!fb) {
        const int base  = segS[gl];
        const int myCnt = cnt[gl];
        const int Tw    = padL[gl];       // uniform across the wave's 8 teams
        const int last  = total - 1;
#pragma unroll 4
        for (int t = half; t < Tw; t += 2) {
            bool act = (t < myCnt);
            int slot = min(base + t, last);
            int sv, kk2;
            if (SRC16) {
                unsigned p = srtPk[slot];
                sv = (int)(p & 0xFFFFu); kk2 = (int)(p >> 16);
            } else {
                sv = (int)srtPk[slot]; kk2 = (int)srtK[slot];
            }
            float4 pc4 = pcmpS[start + kk2];        // broadcast within team
            float xf = act ? x[(sv << 3) + il] : 0.f;
            qa.x += xf * pc4.x;
            qa.y += xf * pc4.y;
            qa.z += xf * pc4.z;
            qa.w += xf * pc4.w;
        }
    } else {
        const float4* pcG = pcmpS + start;
        for (int t = half; t < total; t += 2) {
            unsigned m = meta[start + t];
            if ((int)(m >> 26) == gl) {
                float4 pc4 = pcG[t];
                float xf = x[(size_t)(m & SRCMASK) * CIN + il];
                qa.x += xf * pc4.x;
                qa.y += xf * pc4.y;
                qa.z += xf * pc4.z;
                qa.w += xf * pc4.w;
            }
        }
    }

    // ---- deposit partial Q (channel layout c = (r*8+i)*2+k) ----
    Qbuf[half][gl][2 * il]      = qa.x;
    Qbuf[half][gl][2 * il + 1]  = qa.y;
    Qbuf[half][gl][16 + 2 * il] = qa.z;
    Qbuf[half][gl][17 + 2 * il] = qa.w;
    __syncthreads();   // halves live in different waves

    // ---- epilogue: 16 half-waves x 2 nodes; lane = output channel ----
#pragma unroll
    for (int r = 0; r < 2; ++r) {
        const int gln = sub * 2 + r;      // 0..31
        const int n   = node0 + gln;
        float a0 = 0.f, a1 = 0.f;
#pragma unroll
        for (int ri = 0; ri < NR * CIN; ++ri) {
            float w = sWrad[ri][c];
            a0 += w * (Qbuf[0][gln][2 * ri]     + Qbuf[1][gln][2 * ri]);
            a1 += w * (Qbuf[0][gln][2 * ri + 1] + Qbuf[1][gln][2 * ri + 1]);
        }
        float cs = sPh[c][0], sn = sPh[c][1];
        float re = a0 * cs - a1 * sn;
        float im = a0 * sn + a1 * cs;
        float mag = sqrtf(re * re + im * im + EPSF);
        float sc  = fmaxf(mag + sBias[0][c], 0.f) / mag;
        re *= sc; im *= sc;
#pragma unroll
        for (int L = 0; L < 3; ++L) {
            const float* __restrict__ Wl = (L == 0) ? W1 : (L == 1) ? W2 : W3;
            float bb0 = 0.f, bb1 = 0.f;
#pragma unroll
            for (int i = 0; i < COUT; ++i) {
                float w = Wl[i * COUT + c];
                bb0 += w * __shfl(re, i, 32);
                bb1 += w * __shfl(im, i, 32);
            }
            float m2 = sqrtf(bb0 * bb0 + bb1 * bb1 + EPSF);
            float s2 = fmaxf(m2 + sBias[L + 1][c], 0.f) / m2;
            re = bb0 * s2; im = bb1 * s2;
        }
        if (n < N) {
            float2 v; v.x = re; v.y = im;
            *reinterpret_cast<float2*>(out + ((n << 6) + (c << 1))) = v;
        }
    }
}

// ---------------- fallback fused kernel (meta-only, LDS atomics) ------------
__global__ __launch_bounds__(256) void fused_bucket_fallback(
    const float* __restrict__ x, const int* __restrict__ eidx,
    const float* __restrict__ pcmp, const int* __restrict__ bucketBase,
    const unsigned* __restrict__ sorted,
    const float* __restrict__ W_rad, const float* __restrict__ phase,
    const float* __restrict__ b_nl,
    const float* __restrict__ W1, const float* __restrict__ b1,
    const float* __restrict__ W2, const float* __restrict__ b2,
    const float* __restrict__ W3, const float* __restrict__ b3,
    float* __restrict__ out, int N)
{
    __shared__ float Q[BNODES][COUT];
    __shared__ float sWrad[NR * CIN][COUT];
    __shared__ float sW[3][COUT][COUT];
    __shared__ float sPh[COUT][2];
    __shared__ float sBias[4][COUT];

    for (int i = threadIdx.x; i < BNODES * COUT; i += 256) ((float*)Q)[i] = 0.f;
    for (int i = threadIdx.x; i < NR * CIN * COUT; i += 256) ((float*)sWrad)[i] = W_rad[i];
    for (int i = threadIdx.x; i < COUT * COUT; i += 256) {
        ((float*)sW[0])[i] = W1[i];
        ((float*)sW[1])[i] = W2[i];
        ((float*)sW[2])[i] = W3[i];
    }
    if (threadIdx.x < COUT) {
        float sn, cs; __sincosf(phase[threadIdx.x], &sn, &cs);
        sPh[threadIdx.x][0] = cs; sPh[threadIdx.x][1] = sn;
        sBias[0][threadIdx.x] = b_nl[threadIdx.x];
        sBias[1][threadIdx.x] = b1[threadIdx.x];
        sBias[2][threadIdx.x] = b2[threadIdx.x];
        sBias[3][threadIdx.x] = b3[threadIdx.x];
    }
    __syncthreads();

    const int c   = threadIdx.x & 31;
    const int sub = threadIdx.x >> 5;
    const int i_idx  = (c >> 1) & 7;
    const int pc_off = ((c >> 4) << 1) | (c & 1);
    const int start = bucketBase[blockIdx.x];
    const int end   = bucketBase[blockIdx.x + 1];

    for (int p = start + sub; p < end; p += 8) {
        unsigned v0 = sorted[p];
        int id0 = v0 & IDMASK;
        int s0 = eidx[id0];
        atomicAdd(&Q[v0 >> IDBITS][c],
                  x[(size_t)s0 * CIN + i_idx] * pcmp[(size_t)id0 * 4 + pc_off]);
    }
    __syncthreads();

    const int node0 = blockIdx.x << BSH;
#pragma unroll
    for (int r = 0; r < 4; ++r) {
        const int gl = r * 8 + sub;
        const int n  = node0 + gl;
        float a0 = 0.f, a1 = 0.f;
#pragma unroll
        for (int ri = 0; ri < NR * CIN; ++ri) {
            float w = sWrad[ri][c];
            a0 += w * Q[gl][2 * ri];
            a1 += w * Q[gl][2 * ri + 1];
        }
        float cs = sPh[c][0], sn = sPh[c][1];
        float re = a0 * cs - a1 * sn;
        float im = a0 * sn + a1 * cs;
        float mag = sqrtf(re * re + im * im + EPSF);
        float sc  = fmaxf(mag + sBias[0][c], 0.f) / mag;
        re *= sc; im *= sc;
#pragma unroll
        for (int L = 0; L < 3; ++L) {
            float b0 = 0.f, b1v = 0.f;
#pragma unroll
            for (int i = 0; i < COUT; ++i) {
                float w = sW[L][i][c];
                b0  += w * __shfl(re, i, 32);
                b1v += w * __shfl(im, i, 32);
            }
            float m2 = sqrtf(b0 * b0 + b1v * b1v + EPSF);
            float s2 = fmaxf(m2 + sBias[L + 1][c], 0.f) / m2;
            re = b0 * s2; im = b1v * s2;
        }
        if (n < N) {
            float2 v; v.x = re; v.y = im;
            *reinterpret_cast<float2*>(out + ((size_t)n * COUT + c) * 2) = v;
        }
    }
}

extern "C" void kernel_launch(void* const* d_in, const int* in_sizes, int n_in,
                              void* d_out, int out_size, void* d_ws, size_t ws_size,
                              hipStream_t stream)
{
    const float* x     = (const float*)d_in[0];
    const int*   eidx  = (const int*)  d_in[1];
    const float* pcmp  = (const float*)d_in[2];
    const float* W_rad = (const float*)d_in[3];
    const float* phase = (const float*)d_in[4];
    const float* b_nl  = (const float*)d_in[5];
    const float* W1    = (const float*)d_in[6];
    const float* b1    = (const float*)d_in[7];
    const float* W2    = (const float*)d_in[8];
    const float* b2    = (const float*)d_in[9];
    const float* W3    = (const float*)d_in[10];
    const float* b3    = (const float*)d_in[11];
    float* out = (float*)d_out;

    const int N = in_sizes[0] / CIN;
    const int E = in_sizes[1] / 2;
    const int nb = (N + BNODES - 1) >> BSH;
    const int nchunk = (E + CHUNK - 1) / CHUNK;

    // PACKED layout: pcmpS[E] (16B) | meta[E] (4B) | bucketCnt | bucketBase | gCursor
    float4*   pcmpS      = (float4*)d_ws;
    unsigned* meta       = (unsigned*)(pcmpS + E);
    int*      bucketCnt  = (int*)(meta + E);
    int*      bucketBase = bucketCnt + NBMAX;
    int*      gCursor    = bucketBase + NBMAX + 1;
    size_t needed = (size_t)((char*)(gCursor + NBMAX) - (char*)d_ws);

    if (ws_size >= needed) {
        hipMemsetAsync(bucketCnt, 0, (size_t)nb * sizeof(int), stream);
        bucket_hist<<<256, 256, 0, stream>>>(eidx, bucketCnt, E, nb);
        scan_init<<<1, 1024, 0, stream>>>(bucketCnt, bucketBase, gCursor, nb);
        binify<true><<<nchunk, BINT, 0, stream>>>(eidx, gCursor, meta, pcmpS, pcmp, E, nb);
        if (N <= 65536) {
            fused_team_kernel<true><<<nb, FTH, 0, stream>>>(
                x, pcmpS, meta, bucketBase,
                W_rad, phase, b_nl, W1, b1, W2, b2, W3, b3, out, N);
        } else {
            fused_team_kernel<false><<<nb, FTH, 0, stream>>>(
                x, pcmpS, meta, bucketBase,
                W_rad, phase, b_nl, W1, b1, W2, b2, W3, b3, out, N);
        }
    } else {
        int*      bc = (int*)d_ws;
        int*      bb = bc + NBMAX;
        int*      gc = bb + NBMAX + 1;
        unsigned* so = (unsigned*)(gc + NBMAX);
        hipMemsetAsync(bc, 0, (size_t)nb * sizeof(int), stream);
        bucket_hist<<<256, 256, 0, stream>>>(eidx, bc, E, nb);
        scan_init<<<1, 1024, 0, stream>>>(bc, bb, gc, nb);
        binify<false><<<nchunk, BINT, 0, stream>>>(eidx, gc, so, nullptr, pcmp, E, nb);
        fused_bucket_fallback<<<nb, 256, 0, stream>>>(
            x, eidx, pcmp, bb, so,
            W_rad, phase, b_nl, W1, b1, W2, b2, W3, b3, out, N);
    }
}

// Round 24
// 164.268 us; speedup vs baseline: 1.0559x; 1.0559x over previous
//
#include <hip/hip_runtime.h>

#define CIN 8
#define COUT 32
#define NR 2
#define EPSF 1e-6f

#define BSH 5                   // log2 nodes per bucket
#define BNODES 32               // nodes per bucket
#define NBMAX 2048              // supports N <= 65536
#define CHUNK 4096              // edges per binify block
#define BINT 512                // binify threads
#define BREG (CHUNK / BINT)     // staged edges per binify thread
#define IDBITS 21               // supports E < 2^21
#define IDMASK ((1u << IDBITS) - 1u)
#define SRCMASK 0x03FFFFFFu     // low 26 bits of meta = src node
#define PSTAGE 1792             // per-bucket staging capacity (avg 1024)
#define AREG (PSTAGE / 256)     // phase-A records per thread

// ---------------- pass 1: coarse bucket histogram ----------------
__global__ __launch_bounds__(256) void bucket_hist(
    const int* __restrict__ eidx, int* __restrict__ bucketCnt, int E, int nb)
{
    __shared__ int cnt[NBMAX];
    for (int i = threadIdx.x; i < nb; i += 256) cnt[i] = 0;
    __syncthreads();
    for (int e = blockIdx.x * 256 + threadIdx.x; e < E; e += gridDim.x * 256)
        atomicAdd(&cnt[eidx[E + e] >> BSH], 1);
    __syncthreads();
    for (int i = threadIdx.x; i < nb; i += 256)
        if (cnt[i]) atomicAdd(&bucketCnt[i], cnt[i]);
}

// ---------------- pass 2: single-block scan -> bucket bases ----------------
__global__ __launch_bounds__(1024) void scan_init(
    const int* __restrict__ bucketCnt, int* __restrict__ bucketBase,
    int* __restrict__ gCursor, int nb)
{
    __shared__ int sA[NBMAX], sB[NBMAX];
    for (int i = threadIdx.x; i < NBMAX; i += 1024)
        sA[i] = (i < nb) ? bucketCnt[i] : 0;
    __syncthreads();
    int* src = sA; int* dst = sB;
    for (int off = 1; off < NBMAX; off <<= 1) {
        for (int i = threadIdx.x; i < NBMAX; i += 1024)
            dst[i] = src[i] + (i >= off ? src[i - off] : 0);
        __syncthreads();
        int* tmp = src; src = dst; dst = tmp;
    }
    for (int i = threadIdx.x; i < nb; i += 1024) {
        int incl = src[i];
        int base = incl - bucketCnt[i];
        bucketBase[i] = base;
        gCursor[i] = base;
        if (i == nb - 1) bucketBase[nb] = incl;
    }
}

// ------- pass 3: bin edges by bucket; fast hierarchical scan --------
template<bool PACKED>
__global__ __launch_bounds__(BINT) void binify(
    const int* __restrict__ eidx, int* __restrict__ gCursor,
    unsigned* __restrict__ outMeta,     // PACKED: (dl<<26)|src ; else (dl<<21)|e
    float4*   __restrict__ pcmpS,       // PACKED only: reordered pcmp
    const float* __restrict__ pcmp, int E, int nb)
{
    __shared__ int cnt[NBMAX];
    __shared__ int sIncl[NBMAX];
    __shared__ int gbase[NBMAX];
    __shared__ int wsum[8];
    __shared__ unsigned sid[CHUNK];
    __shared__ unsigned short bucketOf[CHUNK];

    const int e0 = blockIdx.x * CHUNK;
    const int num = min(CHUNK, E - e0);
    const int t = threadIdx.x;
    const int lane = t & 63, wid = t >> 6;

    for (int i = t; i < nb; i += BINT) cnt[i] = 0;
    __syncthreads();

    int dreg[BREG];
#pragma unroll
    for (int kk = 0; kk < BREG; ++kk) {
        int k = t + kk * BINT;
        if (k < num) {
            dreg[kk] = eidx[E + e0 + k];
            atomicAdd(&cnt[dreg[kk] >> BSH], 1);
        }
    }
    __syncthreads();

    {
        int j0 = t * 4;
        int v0 = (j0 + 0 < nb) ? cnt[j0 + 0] : 0;
        int v1 = (j0 + 1 < nb) ? cnt[j0 + 1] : 0;
        int v2 = (j0 + 2 < nb) ? cnt[j0 + 2] : 0;
        int v3 = (j0 + 3 < nb) ? cnt[j0 + 3] : 0;
        int p0 = v0, p1 = p0 + v1, p2 = p1 + v2, p3 = p2 + v3;
        int incl = p3;
#pragma unroll
        for (int off = 1; off < 64; off <<= 1) {
            int u = __shfl_up(incl, off, 64);
            if (lane >= off) incl += u;
        }
        int laneEx = incl - p3;
        if (lane == 63) wsum[wid] = incl;
        __syncthreads();
        if (t == 0) {
            int acc = 0;
#pragma unroll
            for (int i = 0; i < 8; ++i) { int w = wsum[i]; wsum[i] = acc; acc += w; }
        }
        __syncthreads();
        int off0 = wsum[wid] + laneEx;
        sIncl[j0 + 0] = off0 + p0;
        sIncl[j0 + 1] = off0 + p1;
        sIncl[j0 + 2] = off0 + p2;
        sIncl[j0 + 3] = off0 + p3;
    }
    __syncthreads();

    for (int b = t; b < nb; b += BINT) {
        int c = sIncl[b] - (b ? sIncl[b - 1] : 0);
        gbase[b] = c ? atomicAdd(&gCursor[b], c) : 0;
    }
    __syncthreads();
    for (int i = t; i < nb; i += BINT) cnt[i] = 0;   // reuse as cursor
    __syncthreads();

#pragma unroll
    for (int kk = 0; kk < BREG; ++kk) {
        int k = t + kk * BINT;
        if (k < num) {
            int e = e0 + k;
            int d = dreg[kk];
            int b = d >> BSH;
            int slot = (b ? sIncl[b - 1] : 0) + atomicAdd(&cnt[b], 1);
            sid[slot] = ((unsigned)(d & (BNODES - 1)) << IDBITS) | (unsigned)e;
            bucketOf[slot] = (unsigned short)b;
        }
    }
    __syncthreads();

    for (int s = t; s < num; s += BINT) {
        int b = bucketOf[s];
        int intra = s - (b ? sIncl[b - 1] : 0);
        unsigned v = sid[s];
        int pos = gbase[b] + intra;
        if (PACKED) {
            int id = v & IDMASK;
            unsigned dl = v >> IDBITS;
            unsigned sv = (unsigned)eidx[id];
            outMeta[pos] = (dl << 26) | sv;
            pcmpS[pos] = *reinterpret_cast<const float4*>(pcmp + (size_t)id * 4);
        } else {
            outMeta[pos] = v;
        }
    }
}

// ---- pass 4: light-LDS team kernel; explicit 4-batch branch-free loop ----
template<bool SRC16>
__global__ __launch_bounds__(256, 6) void fused_team_kernel(
    const float* __restrict__ x,          // [N, CIN]
    const float4* __restrict__ pcmpS,     // reordered pcmp, bucket-segmented
    const unsigned* __restrict__ meta,    // (dl<<26)|src per slot
    const int* __restrict__ bucketBase,   // [nb+1]
    const float* __restrict__ W_rad, const float* __restrict__ phase,
    const float* __restrict__ b_nl,
    const float* __restrict__ W1, const float* __restrict__ b1,
    const float* __restrict__ W2, const float* __restrict__ b2,
    const float* __restrict__ W3, const float* __restrict__ b3,
    float* __restrict__ out, int N)
{
    __shared__ float sWrad[NR * CIN][COUT];          // 2 KB
    __shared__ float sPh[COUT][2];
    __shared__ float sBias[4][COUT];
    __shared__ unsigned srtPk[PSTAGE];               // 7 KB: (k<<16|src) or src
    __shared__ unsigned short srtK[SRC16 ? 2 : PSTAGE];
    __shared__ float Qbuf[BNODES][33];               // 4.2 KB
    __shared__ int cnt[BNODES], segS[BNODES], cur[BNODES];

    for (int i = threadIdx.x; i < NR * CIN * COUT; i += 256) ((float*)sWrad)[i] = W_rad[i];
    if (threadIdx.x < COUT) {
        float sn, cs; __sincosf(phase[threadIdx.x], &sn, &cs);
        sPh[threadIdx.x][0] = cs; sPh[threadIdx.x][1] = sn;
        sBias[0][threadIdx.x] = b_nl[threadIdx.x];
        sBias[1][threadIdx.x] = b1[threadIdx.x];
        sBias[2][threadIdx.x] = b2[threadIdx.x];
        sBias[3][threadIdx.x] = b3[threadIdx.x];
    }
    if (threadIdx.x < BNODES) cnt[threadIdx.x] = 0;

    const int start = bucketBase[blockIdx.x];
    const int total = bucketBase[blockIdx.x + 1] - start;
    const bool fb = (total > PSTAGE);    // block-uniform fallback flag
    __syncthreads();

    // ---- phase A: coalesced meta load into registers, LDS histogram ----
    unsigned mreg[AREG];
    const int staged = fb ? 0 : total;
#pragma unroll
    for (int kk = 0; kk < AREG; ++kk) {
        int k = threadIdx.x + (kk << 8);
        if (k < staged) {
            mreg[kk] = meta[start + k];
            atomicAdd(&cnt[mreg[kk] >> 26], 1);
        }
    }
    __syncthreads();

    // ---- phase B: exclusive scan of raw counts ----
    if (threadIdx.x < BNODES) {
        int v = cnt[threadIdx.x];
        int incl = v;
#pragma unroll
        for (int off = 1; off < BNODES; off <<= 1) {
            int u = __shfl_up(incl, off, 32);
            if ((int)threadIdx.x >= off) incl += u;
        }
        segS[threadIdx.x] = incl - v;
        cur[threadIdx.x]  = incl - v;
    }
    __syncthreads();

    // ---- phase C: scatter sort tokens into node-sorted LDS ----
    if (!fb) {
#pragma unroll
        for (int kk = 0; kk < AREG; ++kk) {
            int k = threadIdx.x + (kk << 8);
            if (k < staged) {
                unsigned m = mreg[kk];
                int pos = atomicAdd(&cur[m >> 26], 1);
                if (SRC16) {
                    srtPk[pos] = ((unsigned)k << 16) | (m & 0xFFFFu);
                } else {
                    srtPk[pos] = m & SRCMASK;
                    srtK[pos] = (unsigned short)k;
                }
            }
        }
    }
    __syncthreads();

    const int c    = threadIdx.x & 31;    // half-wave lane
    const int sub  = threadIdx.x >> 5;    // half-wave 0..7
    const int team = c >> 3;              // 0..3
    const int il   = c & 7;               // input channel i
    const int gl   = sub * 4 + team;      // node slot 0..31
    const int node0 = blockIdx.x << BSH;

    // ---- team accumulation: explicit 4-batch, branch-free body ----
    float4 qa = {0.f, 0.f, 0.f, 0.f};
    if (!fb) {
        const int base  = segS[gl];
        const int myCnt = cnt[gl];
        const float4* __restrict__ pcb = pcmpS + start;
        int t = 0;
        for (; t + 4 <= myCnt; t += 4) {
            int s0, s1, s2, s3, k0, k1, k2, k3;
            if (SRC16) {
                unsigned p0 = srtPk[base + t],     p1 = srtPk[base + t + 1];
                unsigned p2 = srtPk[base + t + 2], p3 = srtPk[base + t + 3];
                s0 = (int)(p0 & 0xFFFFu); k0 = (int)(p0 >> 16);
                s1 = (int)(p1 & 0xFFFFu); k1 = (int)(p1 >> 16);
                s2 = (int)(p2 & 0xFFFFu); k2 = (int)(p2 >> 16);
                s3 = (int)(p3 & 0xFFFFu); k3 = (int)(p3 >> 16);
            } else {
                s0 = (int)srtPk[base + t];     k0 = srtK[base + t];
                s1 = (int)srtPk[base + t + 1]; k1 = srtK[base + t + 1];
                s2 = (int)srtPk[base + t + 2]; k2 = srtK[base + t + 2];
                s3 = (int)srtPk[base + t + 3]; k3 = srtK[base + t + 3];
            }
            float4 c0 = pcb[k0];
            float4 c1 = pcb[k1];
            float4 c2 = pcb[k2];
            float4 c3 = pcb[k3];
            float x0 = x[(s0 << 3) + il];
            float x1 = x[(s1 << 3) + il];
            float x2 = x[(s2 << 3) + il];
            float x3 = x[(s3 << 3) + il];
            qa.x += x0 * c0.x; qa.y += x0 * c0.y; qa.z += x0 * c0.z; qa.w += x0 * c0.w;
            qa.x += x1 * c1.x; qa.y += x1 * c1.y; qa.z += x1 * c1.z; qa.w += x1 * c1.w;
            qa.x += x2 * c2.x; qa.y += x2 * c2.y; qa.z += x2 * c2.z; qa.w += x2 * c2.w;
            qa.x += x3 * c3.x; qa.y += x3 * c3.y; qa.z += x3 * c3.z; qa.w += x3 * c3.w;
        }
        for (; t < myCnt; ++t) {
            int sv, kv;
            if (SRC16) {
                unsigned p = srtPk[base + t];
                sv = (int)(p & 0xFFFFu); kv = (int)(p >> 16);
            } else {
                sv = (int)srtPk[base + t]; kv = srtK[base + t];
            }
            float4 pc4 = pcb[kv];
            float xf = x[(sv << 3) + il];
            qa.x += xf * pc4.x;
            qa.y += xf * pc4.y;
            qa.z += xf * pc4.z;
            qa.w += xf * pc4.w;
        }
    } else {
        const float4* pcG = pcmpS + start;
        for (int t = 0; t < total; ++t) {
            unsigned m = meta[start + t];
            if ((int)(m >> 26) == gl) {
                float4 pc4 = pcG[t];
                float xf = x[(size_t)(m & SRCMASK) * CIN + il];
                qa.x += xf * pc4.x;
                qa.y += xf * pc4.y;
                qa.z += xf * pc4.z;
                qa.w += xf * pc4.w;
            }
        }
    }

    // ---- deposit Q into LDS (channel layout c = (r*8+i)*2+k) ----
    Qbuf[gl][2 * il]      = qa.x;
    Qbuf[gl][2 * il + 1]  = qa.y;
    Qbuf[gl][16 + 2 * il] = qa.z;
    Qbuf[gl][17 + 2 * il] = qa.w;
    // no barrier: each wave reads only rows its own lanes wrote

    // ---- epilogue: lane = output channel, W read from global (L1/L2-hot) ---
#pragma unroll
    for (int r = 0; r < 4; ++r) {
        const int gln = sub * 4 + r;
        const int n   = node0 + gln;
        float a0 = 0.f, a1 = 0.f;
#pragma unroll
        for (int ri = 0; ri < NR * CIN; ++ri) {
            float w = sWrad[ri][c];
            a0 += w * Qbuf[gln][2 * ri];
            a1 += w * Qbuf[gln][2 * ri + 1];
        }
        float cs = sPh[c][0], sn = sPh[c][1];
        float re = a0 * cs - a1 * sn;
        float im = a0 * sn + a1 * cs;
        float mag = sqrtf(re * re + im * im + EPSF);
        float sc  = fmaxf(mag + sBias[0][c], 0.f) / mag;
        re *= sc; im *= sc;
#pragma unroll
        for (int L = 0; L < 3; ++L) {
            const float* __restrict__ Wl = (L == 0) ? W1 : (L == 1) ? W2 : W3;
            float bb0 = 0.f, bb1 = 0.f;
#pragma unroll
            for (int i = 0; i < COUT; ++i) {
                float w = Wl[i * COUT + c];
                bb0 += w * __shfl(re, i, 32);
                bb1 += w * __shfl(im, i, 32);
            }
            float m2 = sqrtf(bb0 * bb0 + bb1 * bb1 + EPSF);
            float s2 = fmaxf(m2 + sBias[L + 1][c], 0.f) / m2;
            re = bb0 * s2; im = bb1 * s2;
        }
        if (n < N) {
            float2 v; v.x = re; v.y = im;
            *reinterpret_cast<float2*>(out + ((n << 6) + (c << 1))) = v;
        }
    }
}

// ---------------- fallback fused kernel (meta-only, LDS atomics) ------------
__global__ __launch_bounds__(256) void fused_bucket_fallback(
    const float* __restrict__ x, const int* __restrict__ eidx,
    const float* __restrict__ pcmp, const int* __restrict__ bucketBase,
    const unsigned* __restrict__ sorted,
    const float* __restrict__ W_rad, const float* __restrict__ phase,
    const float* __restrict__ b_nl,
    const float* __restrict__ W1, const float* __restrict__ b1,
    const float* __restrict__ W2, const float* __restrict__ b2,
    const float* __restrict__ W3, const float* __restrict__ b3,
    float* __restrict__ out, int N)
{
    __shared__ float Q[BNODES][COUT];
    __shared__ float sWrad[NR * CIN][COUT];
    __shared__ float sW[3][COUT][COUT];
    __shared__ float sPh[COUT][2];
    __shared__ float sBias[4][COUT];

    for (int i = threadIdx.x; i < BNODES * COUT; i += 256) ((float*)Q)[i] = 0.f;
    for (int i = threadIdx.x; i < NR * CIN * COUT; i += 256) ((float*)sWrad)[i] = W_rad[i];
    for (int i = threadIdx.x; i < COUT * COUT; i += 256) {
        ((float*)sW[0])[i] = W1[i];
        ((float*)sW[1])[i] = W2[i];
        ((float*)sW[2])[i] = W3[i];
    }
    if (threadIdx.x < COUT) {
        float sn, cs; __sincosf(phase[threadIdx.x], &sn, &cs);
        sPh[threadIdx.x][0] = cs; sPh[threadIdx.x][1] = sn;
        sBias[0][threadIdx.x] = b_nl[threadIdx.x];
        sBias[1][threadIdx.x] = b1[threadIdx.x];
        sBias[2][threadIdx.x] = b2[threadIdx.x];
        sBias[3][threadIdx.x] = b3[threadIdx.x];
    }
    __syncthreads();

    const int c   = threadIdx.x & 31;
    const int sub = threadIdx.x >> 5;
    const int i_idx  = (c >> 1) & 7;
    const int pc_off = ((c >> 4) << 1) | (c & 1);
    const int start = bucketBase[blockIdx.x];
    const int end   = bucketBase[blockIdx.x + 1];

    for (int p = start + sub; p < end; p += 8) {
        unsigned v0 = sorted[p];
        int id0 = v0 & IDMASK;
        int s0 = eidx[id0];
        atomicAdd(&Q[v0 >> IDBITS][c],
                  x[(size_t)s0 * CIN + i_idx] * pcmp[(size_t)id0 * 4 + pc_off]);
    }
    __syncthreads();

    const int node0 = blockIdx.x << BSH;
#pragma unroll
    for (int r = 0; r < 4; ++r) {
        const int gl = r * 8 + sub;
        const int n  = node0 + gl;
        float a0 = 0.f, a1 = 0.f;
#pragma unroll
        for (int ri = 0; ri < NR * CIN; ++ri) {
            float w = sWrad[ri][c];
            a0 += w * Q[gl][2 * ri];
            a1 += w * Q[gl][2 * ri + 1];
        }
        float cs = sPh[c][0], sn = sPh[c][1];
        float re = a0 * cs - a1 * sn;
        float im = a0 * sn + a1 * cs;
        float mag = sqrtf(re * re + im * im + EPSF);
        float sc  = fmaxf(mag + sBias[0][c], 0.f) / mag;
        re *= sc; im *= sc;
#pragma unroll
        for (int L = 0; L < 3; ++L) {
            float b0 = 0.f, b1v = 0.f;
#pragma unroll
            for (int i = 0; i < COUT; ++i) {
                float w = sW[L][i][c];
                b0  += w * __shfl(re, i, 32);
                b1v += w * __shfl(im, i, 32);
            }
            float m2 = sqrtf(b0 * b0 + b1v * b1v + EPSF);
            float s2 = fmaxf(m2 + sBias[L + 1][c], 0.f) / m2;
            re = b0 * s2; im = b1v * s2;
        }
        if (n < N) {
            float2 v; v.x = re; v.y = im;
            *reinterpret_cast<float2*>(out + ((size_t)n * COUT + c) * 2) = v;
        }
    }
}

extern "C" void kernel_launch(void* const* d_in, const int* in_sizes, int n_in,
                              void* d_out, int out_size, void* d_ws, size_t ws_size,
                              hipStream_t stream)
{
    const float* x     = (const float*)d_in[0];
    const int*   eidx  = (const int*)  d_in[1];
    const float* pcmp  = (const float*)d_in[2];
    const float* W_rad = (const float*)d_in[3];
    const float* phase = (const float*)d_in[4];
    const float* b_nl  = (const float*)d_in[5];
    const float* W1    = (const float*)d_in[6];
    const float* b1    = (const float*)d_in[7];
    const float* W2    = (const float*)d_in[8];
    const float* b2    = (const float*)d_in[9];
    const float* W3    = (const float*)d_in[10];
    const float* b3    = (const float*)d_in[11];
    float* out = (float*)d_out;

    const int N = in_sizes[0] / CIN;
    const int E = in_sizes[1] / 2;
    const int nb = (N + BNODES - 1) >> BSH;
    const int nchunk = (E + CHUNK - 1) / CHUNK;

    // PACKED layout: pcmpS[E] (16B) | meta[E] (4B) | bucketCnt | bucketBase | gCursor
    float4*   pcmpS      = (float4*)d_ws;
    unsigned* meta       = (unsigned*)(pcmpS + E);
    int*      bucketCnt  = (int*)(meta + E);
    int*      bucketBase = bucketCnt + NBMAX;
    int*      gCursor    = bucketBase + NBMAX + 1;
    size_t needed = (size_t)((char*)(gCursor + NBMAX) - (char*)d_ws);

    if (ws_size >= needed) {
        hipMemsetAsync(bucketCnt, 0, (size_t)nb * sizeof(int), stream);
        bucket_hist<<<256, 256, 0, stream>>>(eidx, bucketCnt, E, nb);
        scan_init<<<1, 1024, 0, stream>>>(bucketCnt, bucketBase, gCursor, nb);
        binify<true><<<nchunk, BINT, 0, stream>>>(eidx, gCursor, meta, pcmpS, pcmp, E, nb);
        if (N <= 65536) {
            fused_team_kernel<true><<<nb, 256, 0, stream>>>(
                x, pcmpS, meta, bucketBase,
                W_rad, phase, b_nl, W1, b1, W2, b2, W3, b3, out, N);
        } else {
            fused_team_kernel<false><<<nb, 256, 0, stream>>>(
                x, pcmpS, meta, bucketBase,
                W_rad, phase, b_nl, W1, b1, W2, b2, W3, b3, out, N);
        }
    } else {
        int*      bc = (int*)d_ws;
        int*      bb = bc + NBMAX;
        int*      gc = bb + NBMAX + 1;
        unsigned* so = (unsigned*)(gc + NBMAX);
        hipMemsetAsync(bc, 0, (size_t)nb * sizeof(int), stream);
        bucket_hist<<<256, 256, 0, stream>>>(eidx, bc, E, nb);
        scan_init<<<1, 1024, 0, stream>>>(bc, bb, gc, nb);
        binify<false><<<nchunk, BINT, 0, stream>>>(eidx, gc, so, nullptr, pcmp, E, nb);
        fused_bucket_fallback<<<nb, 256, 0, stream>>>(
            x, eidx, pcmp, bb, so,
            W_rad, phase, b_nl, W1, b1, W2, b2, W3, b3, out, N);
    }
}

// Round 25
// 164.081 us; speedup vs baseline: 1.0571x; 1.0011x over previous
//
#include <hip/hip_runtime.h>

#define CIN 8
#define COUT 32
#define NR 2
#define EPSF 1e-6f

#define BSH 5                   // log2 nodes per bucket
#define BNODES 32               // nodes per bucket
#define NBMAX 2048              // supports N <= 65536
#define CHUNK 4096              // edges per binify block
#define BINT 512                // binify threads
#define BREG (CHUNK / BINT)     // staged edges per binify thread
#define IDBITS 21               // supports E < 2^21
#define IDMASK ((1u << IDBITS) - 1u)
#define SRCMASK 0x03FFFFFFu     // low 26 bits of meta = src node
#define PSTAGE 1792             // per-bucket staging capacity (avg 1024)
#define AREG (PSTAGE / 256)     // phase-A records per thread

// bf16 pack/unpack helpers (RNE rounding)
__device__ __forceinline__ unsigned bf16r(float f) {
    unsigned u = __float_as_uint(f);
    return (u + 0x7FFFu + ((u >> 16) & 1u)) >> 16;
}
__device__ __forceinline__ unsigned pk2(float a, float b) {
    return bf16r(a) | (bf16r(b) << 16);
}
__device__ __forceinline__ float ulo(unsigned w) { return __uint_as_float(w << 16); }
__device__ __forceinline__ float uhi(unsigned w) { return __uint_as_float(w & 0xFFFF0000u); }

// ---------------- pass 1: coarse bucket histogram ----------------
__global__ __launch_bounds__(256) void bucket_hist(
    const int* __restrict__ eidx, int* __restrict__ bucketCnt, int E, int nb)
{
    __shared__ int cnt[NBMAX];
    for (int i = threadIdx.x; i < nb; i += 256) cnt[i] = 0;
    __syncthreads();
    for (int e = blockIdx.x * 256 + threadIdx.x; e < E; e += gridDim.x * 256)
        atomicAdd(&cnt[eidx[E + e] >> BSH], 1);
    __syncthreads();
    for (int i = threadIdx.x; i < nb; i += 256)
        if (cnt[i]) atomicAdd(&bucketCnt[i], cnt[i]);
}

// ---------------- pass 2: single-block scan -> bucket bases ----------------
__global__ __launch_bounds__(1024) void scan_init(
    const int* __restrict__ bucketCnt, int* __restrict__ bucketBase,
    int* __restrict__ gCursor, int nb)
{
    __shared__ int sA[NBMAX], sB[NBMAX];
    for (int i = threadIdx.x; i < NBMAX; i += 1024)
        sA[i] = (i < nb) ? bucketCnt[i] : 0;
    __syncthreads();
    int* src = sA; int* dst = sB;
    for (int off = 1; off < NBMAX; off <<= 1) {
        for (int i = threadIdx.x; i < NBMAX; i += 1024)
            dst[i] = src[i] + (i >= off ? src[i - off] : 0);
        __syncthreads();
        int* tmp = src; src = dst; dst = tmp;
    }
    for (int i = threadIdx.x; i < nb; i += 1024) {
        int incl = src[i];
        int base = incl - bucketCnt[i];
        bucketBase[i] = base;
        gCursor[i] = base;
        if (i == nb - 1) bucketBase[nb] = incl;
    }
}

// ------- pass 3: bin edges by bucket; payload packed to bf16x4 (8B) --------
template<bool PACKED>
__global__ __launch_bounds__(BINT) void binify(
    const int* __restrict__ eidx, int* __restrict__ gCursor,
    unsigned* __restrict__ outMeta,     // PACKED: (dl<<26)|src ; else (dl<<21)|e
    uint2*    __restrict__ pcmpS,       // PACKED only: reordered pcmp (bf16x4)
    const float* __restrict__ pcmp, int E, int nb)
{
    __shared__ int cnt[NBMAX];
    __shared__ int sIncl[NBMAX];
    __shared__ int gbase[NBMAX];
    __shared__ int wsum[8];
    __shared__ unsigned sid[CHUNK];
    __shared__ unsigned short bucketOf[CHUNK];

    const int e0 = blockIdx.x * CHUNK;
    const int num = min(CHUNK, E - e0);
    const int t = threadIdx.x;
    const int lane = t & 63, wid = t >> 6;

    for (int i = t; i < nb; i += BINT) cnt[i] = 0;
    __syncthreads();

    int dreg[BREG];
#pragma unroll
    for (int kk = 0; kk < BREG; ++kk) {
        int k = t + kk * BINT;
        if (k < num) {
            dreg[kk] = eidx[E + e0 + k];
            atomicAdd(&cnt[dreg[kk] >> BSH], 1);
        }
    }
    __syncthreads();

    {
        int j0 = t * 4;
        int v0 = (j0 + 0 < nb) ? cnt[j0 + 0] : 0;
        int v1 = (j0 + 1 < nb) ? cnt[j0 + 1] : 0;
        int v2 = (j0 + 2 < nb) ? cnt[j0 + 2] : 0;
        int v3 = (j0 + 3 < nb) ? cnt[j0 + 3] : 0;
        int p0 = v0, p1 = p0 + v1, p2 = p1 + v2, p3 = p2 + v3;
        int incl = p3;
#pragma unroll
        for (int off = 1; off < 64; off <<= 1) {
            int u = __shfl_up(incl, off, 64);
            if (lane >= off) incl += u;
        }
        int laneEx = incl - p3;
        if (lane == 63) wsum[wid] = incl;
        __syncthreads();
        if (t == 0) {
            int acc = 0;
#pragma unroll
            for (int i = 0; i < 8; ++i) { int w = wsum[i]; wsum[i] = acc; acc += w; }
        }
        __syncthreads();
        int off0 = wsum[wid] + laneEx;
        sIncl[j0 + 0] = off0 + p0;
        sIncl[j0 + 1] = off0 + p1;
        sIncl[j0 + 2] = off0 + p2;
        sIncl[j0 + 3] = off0 + p3;
    }
    __syncthreads();

    for (int b = t; b < nb; b += BINT) {
        int c = sIncl[b] - (b ? sIncl[b - 1] : 0);
        gbase[b] = c ? atomicAdd(&gCursor[b], c) : 0;
    }
    __syncthreads();
    for (int i = t; i < nb; i += BINT) cnt[i] = 0;   // reuse as cursor
    __syncthreads();

#pragma unroll
    for (int kk = 0; kk < BREG; ++kk) {
        int k = t + kk * BINT;
        if (k < num) {
            int e = e0 + k;
            int d = dreg[kk];
            int b = d >> BSH;
            int slot = (b ? sIncl[b - 1] : 0) + atomicAdd(&cnt[b], 1);
            sid[slot] = ((unsigned)(d & (BNODES - 1)) << IDBITS) | (unsigned)e;
            bucketOf[slot] = (unsigned short)b;
        }
    }
    __syncthreads();

    for (int s = t; s < num; s += BINT) {
        int b = bucketOf[s];
        int intra = s - (b ? sIncl[b - 1] : 0);
        unsigned v = sid[s];
        int pos = gbase[b] + intra;
        if (PACKED) {
            int id = v & IDMASK;
            unsigned dl = v >> IDBITS;
            unsigned sv = (unsigned)eidx[id];
            outMeta[pos] = (dl << 26) | sv;
            float4 pc = *reinterpret_cast<const float4*>(pcmp + (size_t)id * 4);
            uint2 pw;
            pw.x = pk2(pc.x, pc.y);
            pw.y = pk2(pc.z, pc.w);
            pcmpS[pos] = pw;
        } else {
            outMeta[pos] = v;
        }
    }
}

// ---- pass 4: light-LDS team kernel; bf16x4 payload, 4-batch loop ----
template<bool SRC16>
__global__ __launch_bounds__(256, 6) void fused_team_kernel(
    const float* __restrict__ x,          // [N, CIN]
    const uint2* __restrict__ pcmpS,      // reordered pcmp (bf16x4)
    const unsigned* __restrict__ meta,    // (dl<<26)|src per slot
    const int* __restrict__ bucketBase,   // [nb+1]
    const float* __restrict__ W_rad, const float* __restrict__ phase,
    const float* __restrict__ b_nl,
    const float* __restrict__ W1, const float* __restrict__ b1,
    const float* __restrict__ W2, const float* __restrict__ b2,
    const float* __restrict__ W3, const float* __restrict__ b3,
    float* __restrict__ out, int N)
{
    __shared__ float sWrad[NR * CIN][COUT];          // 2 KB
    __shared__ float sPh[COUT][2];
    __shared__ float sBias[4][COUT];
    __shared__ unsigned srtPk[PSTAGE];               // 7 KB: (k<<16|src) or src
    __shared__ unsigned short srtK[SRC16 ? 2 : PSTAGE];
    __shared__ float Qbuf[BNODES][33];               // 4.2 KB
    __shared__ int cnt[BNODES], segS[BNODES], cur[BNODES];

    for (int i = threadIdx.x; i < NR * CIN * COUT; i += 256) ((float*)sWrad)[i] = W_rad[i];
    if (threadIdx.x < COUT) {
        float sn, cs; __sincosf(phase[threadIdx.x], &sn, &cs);
        sPh[threadIdx.x][0] = cs; sPh[threadIdx.x][1] = sn;
        sBias[0][threadIdx.x] = b_nl[threadIdx.x];
        sBias[1][threadIdx.x] = b1[threadIdx.x];
        sBias[2][threadIdx.x] = b2[threadIdx.x];
        sBias[3][threadIdx.x] = b3[threadIdx.x];
    }
    if (threadIdx.x < BNODES) cnt[threadIdx.x] = 0;

    const int start = bucketBase[blockIdx.x];
    const int total = bucketBase[blockIdx.x + 1] - start;
    const bool fb = (total > PSTAGE);    // block-uniform fallback flag
    __syncthreads();

    // ---- phase A: coalesced meta load into registers, LDS histogram ----
    unsigned mreg[AREG];
    const int staged = fb ? 0 : total;
#pragma unroll
    for (int kk = 0; kk < AREG; ++kk) {
        int k = threadIdx.x + (kk << 8);
        if (k < staged) {
            mreg[kk] = meta[start + k];
            atomicAdd(&cnt[mreg[kk] >> 26], 1);
        }
    }
    __syncthreads();

    // ---- phase B: exclusive scan of raw counts ----
    if (threadIdx.x < BNODES) {
        int v = cnt[threadIdx.x];
        int incl = v;
#pragma unroll
        for (int off = 1; off < BNODES; off <<= 1) {
            int u = __shfl_up(incl, off, 32);
            if ((int)threadIdx.x >= off) incl += u;
        }
        segS[threadIdx.x] = incl - v;
        cur[threadIdx.x]  = incl - v;
    }
    __syncthreads();

    // ---- phase C: scatter sort tokens into node-sorted LDS ----
    if (!fb) {
#pragma unroll
        for (int kk = 0; kk < AREG; ++kk) {
            int k = threadIdx.x + (kk << 8);
            if (k < staged) {
                unsigned m = mreg[kk];
                int pos = atomicAdd(&cur[m >> 26], 1);
                if (SRC16) {
                    srtPk[pos] = ((unsigned)k << 16) | (m & 0xFFFFu);
                } else {
                    srtPk[pos] = m & SRCMASK;
                    srtK[pos] = (unsigned short)k;
                }
            }
        }
    }
    __syncthreads();

    const int c    = threadIdx.x & 31;    // half-wave lane
    const int sub  = threadIdx.x >> 5;    // half-wave 0..7
    const int team = c >> 3;              // 0..3
    const int il   = c & 7;               // input channel i
    const int gl   = sub * 4 + team;      // node slot 0..31
    const int node0 = blockIdx.x << BSH;

    // ---- team accumulation: explicit 4-batch, branch-free body ----
    float4 qa = {0.f, 0.f, 0.f, 0.f};
    if (!fb) {
        const int base  = segS[gl];
        const int myCnt = cnt[gl];
        const uint2* __restrict__ pcb = pcmpS + start;
        int t = 0;
        for (; t + 4 <= myCnt; t += 4) {
            int s0, s1, s2, s3, k0, k1, k2, k3;
            if (SRC16) {
                unsigned p0 = srtPk[base + t],     p1 = srtPk[base + t + 1];
                unsigned p2 = srtPk[base + t + 2], p3 = srtPk[base + t + 3];
                s0 = (int)(p0 & 0xFFFFu); k0 = (int)(p0 >> 16);
                s1 = (int)(p1 & 0xFFFFu); k1 = (int)(p1 >> 16);
                s2 = (int)(p2 & 0xFFFFu); k2 = (int)(p2 >> 16);
                s3 = (int)(p3 & 0xFFFFu); k3 = (int)(p3 >> 16);
            } else {
                s0 = (int)srtPk[base + t];     k0 = srtK[base + t];
                s1 = (int)srtPk[base + t + 1]; k1 = srtK[base + t + 1];
                s2 = (int)srtPk[base + t + 2]; k2 = srtK[base + t + 2];
                s3 = (int)srtPk[base + t + 3]; k3 = srtK[base + t + 3];
            }
            uint2 w0 = pcb[k0];
            uint2 w1 = pcb[k1];
            uint2 w2 = pcb[k2];
            uint2 w3 = pcb[k3];
            float x0 = x[(s0 << 3) + il];
            float x1 = x[(s1 << 3) + il];
            float x2 = x[(s2 << 3) + il];
            float x3 = x[(s3 << 3) + il];
            qa.x += x0 * ulo(w0.x); qa.y += x0 * uhi(w0.x);
            qa.z += x0 * ulo(w0.y); qa.w += x0 * uhi(w0.y);
            qa.x += x1 * ulo(w1.x); qa.y += x1 * uhi(w1.x);
            qa.z += x1 * ulo(w1.y); qa.w += x1 * uhi(w1.y);
            qa.x += x2 * ulo(w2.x); qa.y += x2 * uhi(w2.x);
            qa.z += x2 * ulo(w2.y); qa.w += x2 * uhi(w2.y);
            qa.x += x3 * ulo(w3.x); qa.y += x3 * uhi(w3.x);
            qa.z += x3 * ulo(w3.y); qa.w += x3 * uhi(w3.y);
        }
        for (; t < myCnt; ++t) {
            int sv, kv;
            if (SRC16) {
                unsigned p = srtPk[base + t];
                sv = (int)(p & 0xFFFFu); kv = (int)(p >> 16);
            } else {
                sv = (int)srtPk[base + t]; kv = srtK[base + t];
            }
            uint2 w = pcb[kv];
            float xf = x[(sv << 3) + il];
            qa.x += xf * ulo(w.x); qa.y += xf * uhi(w.x);
            qa.z += xf * ulo(w.y); qa.w += xf * uhi(w.y);
        }
    } else {
        const uint2* pcG = pcmpS + start;
        for (int t = 0; t < total; ++t) {
            unsigned m = meta[start + t];
            if ((int)(m >> 26) == gl) {
                uint2 w = pcG[t];
                float xf = x[(size_t)(m & SRCMASK) * CIN + il];
                qa.x += xf * ulo(w.x); qa.y += xf * uhi(w.x);
                qa.z += xf * ulo(w.y); qa.w += xf * uhi(w.y);
            }
        }
    }

    // ---- deposit Q into LDS (channel layout c = (r*8+i)*2+k) ----
    Qbuf[gl][2 * il]      = qa.x;
    Qbuf[gl][2 * il + 1]  = qa.y;
    Qbuf[gl][16 + 2 * il] = qa.z;
    Qbuf[gl][17 + 2 * il] = qa.w;
    // no barrier: each wave reads only rows its own lanes wrote

    // ---- epilogue: lane = output channel, W read from global (L1/L2-hot) ---
#pragma unroll
    for (int r = 0; r < 4; ++r) {
        const int gln = sub * 4 + r;
        const int n   = node0 + gln;
        float a0 = 0.f, a1 = 0.f;
#pragma unroll
        for (int ri = 0; ri < NR * CIN; ++ri) {
            float w = sWrad[ri][c];
            a0 += w * Qbuf[gln][2 * ri];
            a1 += w * Qbuf[gln][2 * ri + 1];
        }
        float cs = sPh[c][0], sn = sPh[c][1];
        float re = a0 * cs - a1 * sn;
        float im = a0 * sn + a1 * cs;
        float mag = sqrtf(re * re + im * im + EPSF);
        float sc  = fmaxf(mag + sBias[0][c], 0.f) / mag;
        re *= sc; im *= sc;
#pragma unroll
        for (int L = 0; L < 3; ++L) {
            const float* __restrict__ Wl = (L == 0) ? W1 : (L == 1) ? W2 : W3;
            float bb0 = 0.f, bb1 = 0.f;
#pragma unroll
            for (int i = 0; i < COUT; ++i) {
                float w = Wl[i * COUT + c];
                bb0 += w * __shfl(re, i, 32);
                bb1 += w * __shfl(im, i, 32);
            }
            float m2 = sqrtf(bb0 * bb0 + bb1 * bb1 + EPSF);
            float s2 = fmaxf(m2 + sBias[L + 1][c], 0.f) / m2;
            re = bb0 * s2; im = bb1 * s2;
        }
        if (n < N) {
            float2 v; v.x = re; v.y = im;
            *reinterpret_cast<float2*>(out + ((n << 6) + (c << 1))) = v;
        }
    }
}

// ---------------- fallback fused kernel (meta-only, LDS atomics) ------------
__global__ __launch_bounds__(256) void fused_bucket_fallback(
    const float* __restrict__ x, const int* __restrict__ eidx,
    const float* __restrict__ pcmp, const int* __restrict__ bucketBase,
    const unsigned* __restrict__ sorted,
    const float* __restrict__ W_rad, const float* __restrict__ phase,
    const float* __restrict__ b_nl,
    const float* __restrict__ W1, const float* __restrict__ b1,
    const float* __restrict__ W2, const float* __restrict__ b2,
    const float* __restrict__ W3, const float* __restrict__ b3,
    float* __restrict__ out, int N)
{
    __shared__ float Q[BNODES][COUT];
    __shared__ float sWrad[NR * CIN][COUT];
    __shared__ float sW[3][COUT][COUT];
    __shared__ float sPh[COUT][2];
    __shared__ float sBias[4][COUT];

    for (int i = threadIdx.x; i < BNODES * COUT; i += 256) ((float*)Q)[i] = 0.f;
    for (int i = threadIdx.x; i < NR * CIN * COUT; i += 256) ((float*)sWrad)[i] = W_rad[i];
    for (int i = threadIdx.x; i < COUT * COUT; i += 256) {
        ((float*)sW[0])[i] = W1[i];
        ((float*)sW[1])[i] = W2[i];
        ((float*)sW[2])[i] = W3[i];
    }
    if (threadIdx.x < COUT) {
        float sn, cs; __sincosf(phase[threadIdx.x], &sn, &cs);
        sPh[threadIdx.x][0] = cs; sPh[threadIdx.x][1] = sn;
        sBias[0][threadIdx.x] = b_nl[threadIdx.x];
        sBias[1][threadIdx.x] = b1[threadIdx.x];
        sBias[2][threadIdx.x] = b2[threadIdx.x];
        sBias[3][threadIdx.x] = b3[threadIdx.x];
    }
    __syncthreads();

    const int c   = threadIdx.x & 31;
    const int sub = threadIdx.x >> 5;
    const int i_idx  = (c >> 1) & 7;
    const int pc_off = ((c >> 4) << 1) | (c & 1);
    const int start = bucketBase[blockIdx.x];
    const int end   = bucketBase[blockIdx.x + 1];

    for (int p = start + sub; p < end; p += 8) {
        unsigned v0 = sorted[p];
        int id0 = v0 & IDMASK;
        int s0 = eidx[id0];
        atomicAdd(&Q[v0 >> IDBITS][c],
                  x[(size_t)s0 * CIN + i_idx] * pcmp[(size_t)id0 * 4 + pc_off]);
    }
    __syncthreads();

    const int node0 = blockIdx.x << BSH;
#pragma unroll
    for (int r = 0; r < 4; ++r) {
        const int gl = r * 8 + sub;
        const int n  = node0 + gl;
        float a0 = 0.f, a1 = 0.f;
#pragma unroll
        for (int ri = 0; ri < NR * CIN; ++ri) {
            float w = sWrad[ri][c];
            a0 += w * Q[gl][2 * ri];
            a1 += w * Q[gl][2 * ri + 1];
        }
        float cs = sPh[c][0], sn = sPh[c][1];
        float re = a0 * cs - a1 * sn;
        float im = a0 * sn + a1 * cs;
        float mag = sqrtf(re * re + im * im + EPSF);
        float sc  = fmaxf(mag + sBias[0][c], 0.f) / mag;
        re *= sc; im *= sc;
#pragma unroll
        for (int L = 0; L < 3; ++L) {
            float b0 = 0.f, b1v = 0.f;
#pragma unroll
            for (int i = 0; i < COUT; ++i) {
                float w = sW[L][i][c];
                b0  += w * __shfl(re, i, 32);
                b1v += w * __shfl(im, i, 32);
            }
            float m2 = sqrtf(b0 * b0 + b1v * b1v + EPSF);
            float s2 = fmaxf(m2 + sBias[L + 1][c], 0.f) / m2;
            re = b0 * s2; im = b1v * s2;
        }
        if (n < N) {
            float2 v; v.x = re; v.y = im;
            *reinterpret_cast<float2*>(out + ((size_t)n * COUT + c) * 2) = v;
        }
    }
}

extern "C" void kernel_launch(void* const* d_in, const int* in_sizes, int n_in,
                              void* d_out, int out_size, void* d_ws, size_t ws_size,
                              hipStream_t stream)
{
    const float* x     = (const float*)d_in[0];
    const int*   eidx  = (const int*)  d_in[1];
    const float* pcmp  = (const float*)d_in[2];
    const float* W_rad = (const float*)d_in[3];
    const float* phase = (const float*)d_in[4];
    const float* b_nl  = (const float*)d_in[5];
    const float* W1    = (const float*)d_in[6];
    const float* b1    = (const float*)d_in[7];
    const float* W2    = (const float*)d_in[8];
    const float* b2    = (const float*)d_in[9];
    const float* W3    = (const float*)d_in[10];
    const float* b3    = (const float*)d_in[11];
    float* out = (float*)d_out;

    const int N = in_sizes[0] / CIN;
    const int E = in_sizes[1] / 2;
    const int nb = (N + BNODES - 1) >> BSH;
    const int nchunk = (E + CHUNK - 1) / CHUNK;

    // PACKED layout: pcmpS[E] (8B bf16x4) | meta[E] (4B) | bucketCnt | bucketBase | gCursor
    uint2*    pcmpS      = (uint2*)d_ws;
    unsigned* meta       = (unsigned*)(pcmpS + E);
    int*      bucketCnt  = (int*)(meta + E);
    int*      bucketBase = bucketCnt + NBMAX;
    int*      gCursor    = bucketBase + NBMAX + 1;
    size_t needed = (size_t)((char*)(gCursor + NBMAX) - (char*)d_ws);

    if (ws_size >= needed) {
        hipMemsetAsync(bucketCnt, 0, (size_t)nb * sizeof(int), stream);
        bucket_hist<<<256, 256, 0, stream>>>(eidx, bucketCnt, E, nb);
        scan_init<<<1, 1024, 0, stream>>>(bucketCnt, bucketBase, gCursor, nb);
        binify<true><<<nchunk, BINT, 0, stream>>>(eidx, gCursor, meta, pcmpS, pcmp, E, nb);
        if (N <= 65536) {
            fused_team_kernel<true><<<nb, 256, 0, stream>>>(
                x, pcmpS, meta, bucketBase,
                W_rad, phase, b_nl, W1, b1, W2, b2, W3, b3, out, N);
        } else {
            fused_team_kernel<false><<<nb, 256, 0, stream>>>(
                x, pcmpS, meta, bucketBase,
                W_rad, phase, b_nl, W1, b1, W2, b2, W3, b3, out, N);
        }
    } else {
        int*      bc = (int*)d_ws;
        int*      bb = bc + NBMAX;
        int*      gc = bb + NBMAX + 1;
        unsigned* so = (unsigned*)(gc + NBMAX);
        hipMemsetAsync(bc, 0, (size_t)nb * sizeof(int), stream);
        bucket_hist<<<256, 256, 0, stream>>>(eidx, bc, E, nb);
        scan_init<<<1, 1024, 0, stream>>>(bc, bb, gc, nb);
        binify<false><<<nchunk, BINT, 0, stream>>>(eidx, gc, so, nullptr, pcmp, E, nb);
        fused_bucket_fallback<<<nb, 256, 0, stream>>>(
            x, eidx, pcmp, bb, so,
            W_rad, phase, b_nl, W1, b1, W2, b2, W3, b3, out, N);
    }
}